// Round 1
// baseline (47.236 us; speedup 1.0000x reference)
//
#include <hip/hip_runtime.h>
#include <math.h>

// One block per proposal; 256 threads; each thread owns one gathered point.
// Output per proposal: [mean, median, min, max] of ||pt_offsets[idx]||.
__global__ __launch_bounds__(256) void offs4feat_kernel(
    const int*   __restrict__ prop_offset,   // (P+1,) int32
    const int*   __restrict__ prop_idx,      // (M,2)  int32, col 1 = point id
    const float* __restrict__ pt_offsets,    // (N,3)  f32
    const int*   __restrict__ npoint_ptr,    // scalar int32 (=256)
    float*       __restrict__ out)           // (P,4)  f32
{
    __shared__ float r[256];
    __shared__ float wsum[4], wmin[4], wmax[4];

    const int p  = blockIdx.x;
    const int t  = threadIdx.x;
    const int np = *npoint_ptr;              // 256 in this harness
    const int start = prop_offset[p];

    const bool active = (t < np);
    float radius = 0.0f;
    if (active) {
        const int idx = prop_idx[(size_t)(start + t) * 2 + 1];
        const float x = pt_offsets[(size_t)idx * 3 + 0];
        const float y = pt_offsets[(size_t)idx * 3 + 1];
        const float z = pt_offsets[(size_t)idx * 3 + 2];
        radius = sqrtf(fmaf(x, x, fmaf(y, y, z * z)));
    }
    r[t] = radius;
    __syncthreads();

    // ---- median: rank selection with index tiebreak (matches stable sort) ----
    if (active) {
        const float my = radius;
        int rank = 0;
        #pragma unroll 8
        for (int j = 0; j < np; ++j) {
            const float rj = r[j];                 // broadcast read, conflict-free
            rank += (rj < my || (rj == my && j < t)) ? 1 : 0;
        }
        if (rank == (np - 1) / 2) out[p * 4 + 1] = my;
    }

    // ---- mean / min / max: wave shuffle reduce, then cross-wave combine ----
    float s  = active ? radius : 0.0f;
    float mn = active ? radius : INFINITY;
    float mx = active ? radius : -INFINITY;
    #pragma unroll
    for (int off = 32; off > 0; off >>= 1) {
        s  +=        __shfl_down(s,  off, 64);
        mn = fminf(mn, __shfl_down(mn, off, 64));
        mx = fmaxf(mx, __shfl_down(mx, off, 64));
    }
    const int wave = t >> 6;
    if ((t & 63) == 0) { wsum[wave] = s; wmin[wave] = mn; wmax[wave] = mx; }
    __syncthreads();
    if (t == 0) {
        const int nw = (blockDim.x + 63) >> 6;
        float S = 0.0f, MN = INFINITY, MX = -INFINITY;
        for (int w = 0; w < nw; ++w) {
            S += wsum[w];
            MN = fminf(MN, wmin[w]);
            MX = fmaxf(MX, wmax[w]);
        }
        out[p * 4 + 0] = S / (float)np;
        out[p * 4 + 2] = MN;
        out[p * 4 + 3] = MX;
    }
}

extern "C" void kernel_launch(void* const* d_in, const int* in_sizes, int n_in,
                              void* d_out, int out_size, void* d_ws, size_t ws_size,
                              hipStream_t stream) {
    // d_in order per setup_inputs():
    //   0: semantic_scores (f32, unused — output dtype only)
    //   1: proposals_offset (int32, P+1)
    //   2: proposals_idx    (int32, (M,2))
    //   3: pt_offsets       (f32,  (N,3))
    //   4: min_npoint       (int32 scalar)
    const int*   prop_offset = (const int*)  d_in[1];
    const int*   prop_idx    = (const int*)  d_in[2];
    const float* pt_offsets  = (const float*)d_in[3];
    const int*   npoint_ptr  = (const int*)  d_in[4];
    float*       out         = (float*)      d_out;

    const int n_proposals = in_sizes[1] - 1;   // 4096

    offs4feat_kernel<<<n_proposals, 256, 0, stream>>>(
        prop_offset, prop_idx, pt_offsets, npoint_ptr, out);
}

// Round 2
// 27.964 us; speedup vs baseline: 1.6892x; 1.6892x over previous
//
#include <hip/hip_runtime.h>
#include <math.h>

// One block per proposal; 256 threads; each thread owns one gathered point.
// Output per proposal: [mean, median, min, max] of ||pt_offsets[idx]||.
// Median/min/max via a full bitonic sort of the 256 radii (value at a fixed
// sorted index is tie-order independent, so no tiebreak needed).
__global__ __launch_bounds__(256) void offs4feat_kernel(
    const int*   __restrict__ prop_offset,   // (P+1,) int32
    const int*   __restrict__ prop_idx,      // (M,2)  int32, col 1 = point id
    const float* __restrict__ pt_offsets,    // (N,3)  f32
    const int*   __restrict__ npoint_ptr,    // scalar int32 (=256)
    float*       __restrict__ out)           // (P,4)  f32
{
    __shared__ float sh[256];
    __shared__ float wsum[4];

    const int p  = blockIdx.x;
    const int t  = threadIdx.x;
    const int np = *npoint_ptr;              // 256 in this harness
    const int start = prop_offset[p];

    const bool active = (t < np);
    float radius = INFINITY;                 // pad sorts to the end
    if (active) {
        const int idx = prop_idx[(size_t)(start + t) * 2 + 1];
        const float x = pt_offsets[(size_t)idx * 3 + 0];
        const float y = pt_offsets[(size_t)idx * 3 + 1];
        const float z = pt_offsets[(size_t)idx * 3 + 2];
        radius = sqrtf(fmaf(x, x, fmaf(y, y, z * z)));
    }

    // ---- mean: wave shuffle reduce + cross-wave combine (before sort) ----
    float s = active ? radius : 0.0f;
    #pragma unroll
    for (int off = 32; off > 0; off >>= 1)
        s += __shfl_down(s, off, 64);
    const int wave = t >> 6;
    if ((t & 63) == 0) wsum[wave] = s;

    // ---- bitonic sort of radius across the 256 threads ----
    float v = radius;
    #pragma unroll
    for (int k = 2; k <= 256; k <<= 1) {
        // cross-wave stages (stride >= 64) via LDS
        #pragma unroll
        for (int j = k >> 1; j >= 64; j >>= 1) {
            __syncthreads();
            sh[t] = v;
            __syncthreads();
            const float o = sh[t ^ j];
            const bool keep_min = (((t & k) == 0) == ((t & j) == 0));
            v = keep_min ? fminf(v, o) : fmaxf(v, o);
        }
        // intra-wave stages via shuffle
        #pragma unroll
        for (int j = (k >> 1) < 32 ? (k >> 1) : 32; j >= 1; j >>= 1) {
            const float o = __shfl_xor(v, j, 64);
            const bool keep_min = (((t & k) == 0) == ((t & j) == 0));
            v = keep_min ? fminf(v, o) : fmaxf(v, o);
        }
    }
    // now v == sorted[t] (inactive pads are +INF at the tail)

    __syncthreads();   // wsum ready (also orders last LDS sort stage)

    if (t == 0) {
        float S = 0.0f;
        const int nw = (blockDim.x + 63) >> 6;
        for (int w = 0; w < nw; ++w) S += wsum[w];
        out[p * 4 + 0] = S / (float)np;
        out[p * 4 + 2] = v;                 // sorted[0] = min
    }
    if (t == (np - 1) / 2) out[p * 4 + 1] = v;   // median
    if (t == np - 1)       out[p * 4 + 3] = v;   // max
}

extern "C" void kernel_launch(void* const* d_in, const int* in_sizes, int n_in,
                              void* d_out, int out_size, void* d_ws, size_t ws_size,
                              hipStream_t stream) {
    // d_in order per setup_inputs():
    //   0: semantic_scores (f32, unused — output dtype only)
    //   1: proposals_offset (int32, P+1)
    //   2: proposals_idx    (int32, (M,2))
    //   3: pt_offsets       (f32,  (N,3))
    //   4: min_npoint       (int32 scalar)
    const int*   prop_offset = (const int*)  d_in[1];
    const int*   prop_idx    = (const int*)  d_in[2];
    const float* pt_offsets  = (const float*)d_in[3];
    const int*   npoint_ptr  = (const int*)  d_in[4];
    float*       out         = (float*)      d_out;

    const int n_proposals = in_sizes[1] - 1;   // 4096

    offs4feat_kernel<<<n_proposals, 256, 0, stream>>>(
        prop_offset, prop_idx, pt_offsets, npoint_ptr, out);
}